// Round 1
// baseline (83.503 us; speedup 1.0000x reference)
//
#include <hip/hip_runtime.h>

// Problem shape (fixed by the reference setup)
#define TT 512
#define BB 32
#define FF 256
#define LL 8
// B*F*L = 65536, F*L = 2048

__global__ __launch_bounds__(256) void trace_rnn_kernel(
    const float* __restrict__ features,  // [T,B,F]
    const int*   __restrict__ resets,    // [T,B]
    const float* __restrict__ carry,     // [B,F,L]
    const float* __restrict__ lambdas,   // [L]
    float*       __restrict__ out)       // [B*F*L] final, then [T,B,F*L] ys
{
    // gid in [0, B*F*L). Each 256-thread block lies within a single b
    // (F*L = 2048 = 8 blocks per b), so derive b from blockIdx only ->
    // resets load is wave-uniform (scalar load).
    const int b  = blockIdx.x >> 3;                       // gid >> 11
    const int fl = ((blockIdx.x & 7) << 8) | threadIdx.x; // gid & 2047
    const int f  = fl >> 3;
    const int l  = fl & 7;
    const int gid = (b << 11) | fl;

    const float lam   = lambdas[l];
    const float one_m = 1.0f - lam;

    float trace = carry[gid];

    const float* fptr = features + b * FF + f;   // stride B*F per t
    const int*   rptr = resets + b;              // stride B per t
    float*       yptr = out + BB * FF * LL + gid; // ys base, stride B*F*L per t

    #pragma unroll 4
    for (int t = 0; t < TT; ++t) {
        const float x = fptr[(size_t)t * (BB * FF)];
        const int   r = rptr[(size_t)t * BB];
        const float v = fmaf(lam, trace, one_m * x);
        trace = r ? x : v;
        yptr[(size_t)t * (BB * FF * LL)] = trace;
    }

    // final_trace is the FIRST output in the concatenation
    out[gid] = trace;
}

extern "C" void kernel_launch(void* const* d_in, const int* in_sizes, int n_in,
                              void* d_out, int out_size, void* d_ws, size_t ws_size,
                              hipStream_t stream) {
    const float* features = (const float*)d_in[0];
    const int*   resets   = (const int*)d_in[1];
    const float* carry    = (const float*)d_in[2];
    const float* lambdas  = (const float*)d_in[3];
    float* out = (float*)d_out;

    const int total = BB * FF * LL;  // 65536 threads
    trace_rnn_kernel<<<total / 256, 256, 0, stream>>>(features, resets, carry, lambdas, out);
}

// Round 2
// 47.683 us; speedup vs baseline: 1.7512x; 1.7512x over previous
//
#include <hip/hip_runtime.h>

// Problem shape (fixed by the reference setup)
#define TT 512
#define BB 32
#define FF 256
#define LL 8
#define NCHAIN (BB * FF * LL)   // 65536 independent chains
#define NCHUNK 8
#define TC (TT / NCHUNK)        // 64 steps per chunk

// Thread decomposition (both kernels): gid = chunk*NCHAIN + chain.
// 256 blocks per chunk; within a chunk, 8 blocks per b (F*L=2048), so both
// `chunk` and `b` are block-uniform -> resets load is a scalar broadcast.

// Phase 1: per (chain, chunk) compute the chunk's composed affine map:
//   A = prod of a_t,  E = scan end-value starting from state 0.
__global__ __launch_bounds__(256) void phase1_kernel(
    const float* __restrict__ features,  // [T,B,F]
    const int*   __restrict__ resets,    // [T,B]
    const float* __restrict__ lambdas,   // [L]
    float*       __restrict__ wsA,       // [NCHUNK][NCHAIN]
    float*       __restrict__ wsE)       // [NCHUNK][NCHAIN]
{
    const int chunk      = blockIdx.x >> 8;
    const int blockLocal = blockIdx.x & 255;
    const int b  = blockLocal >> 3;
    const int fl = ((blockLocal & 7) << 8) | threadIdx.x;
    const int f  = fl >> 3;
    const int l  = fl & 7;
    const int chain = (b << 11) | fl;

    const float lam  = lambdas[l];
    const float onem = 1.0f - lam;
    const int   t0   = chunk * TC;

    const float* fptr = features + (size_t)t0 * (BB * FF) + b * FF + f;
    const int*   rptr = resets + (size_t)t0 * BB + b;

    float A = 1.0f, E = 0.0f;
    #pragma unroll 8
    for (int t = 0; t < TC; ++t) {
        const float x  = fptr[(size_t)t * (BB * FF)];
        const int   r  = rptr[(size_t)t * BB];
        const float Av = A * lam;
        const float Ev = fmaf(lam, E, onem * x);
        A = r ? 0.0f : Av;
        E = r ? x : Ev;
    }
    wsA[(size_t)chunk * NCHAIN + chain] = A;
    wsE[(size_t)chunk * NCHAIN + chain] = E;
}

// Phase 2: fold preceding chunk maps into the true initial state, then
// replay the chunk's scan writing every step.
__global__ __launch_bounds__(256) void phase2_kernel(
    const float* __restrict__ features,
    const int*   __restrict__ resets,
    const float* __restrict__ carry,     // [B,F,L] == [NCHAIN]
    const float* __restrict__ lambdas,
    const float* __restrict__ wsA,
    const float* __restrict__ wsE,
    float*       __restrict__ out)       // [NCHAIN] final, then [T][NCHAIN] ys
{
    const int chunk      = blockIdx.x >> 8;
    const int blockLocal = blockIdx.x & 255;
    const int b  = blockLocal >> 3;
    const int fl = ((blockLocal & 7) << 8) | threadIdx.x;
    const int f  = fl >> 3;
    const int l  = fl & 7;
    const int chain = (b << 11) | fl;

    const float lam  = lambdas[l];
    const float onem = 1.0f - lam;
    const int   t0   = chunk * TC;

    // True initial state for this chunk: fold carry through chunks [0, chunk).
    float s = carry[chain];
    for (int cc = 0; cc < chunk; ++cc) {
        s = fmaf(wsA[(size_t)cc * NCHAIN + chain], s,
                 wsE[(size_t)cc * NCHAIN + chain]);
    }

    const float* fptr = features + (size_t)t0 * (BB * FF) + b * FF + f;
    const int*   rptr = resets + (size_t)t0 * BB + b;
    float*       yptr = out + NCHAIN + (size_t)t0 * NCHAIN + chain;

    #pragma unroll 4
    for (int t = 0; t < TC; ++t) {
        const float x = fptr[(size_t)t * (BB * FF)];
        const int   r = rptr[(size_t)t * BB];
        const float v = fmaf(lam, s, onem * x);
        s = r ? x : v;
        yptr[(size_t)t * NCHAIN] = s;
    }

    // Last chunk's end state is the final trace (FIRST output in concat).
    if (chunk == NCHUNK - 1) out[chain] = s;
}

// Fallback (ws too small): the round-1 single-pass kernel, known correct.
__global__ __launch_bounds__(256) void trace_rnn_fallback(
    const float* __restrict__ features,
    const int*   __restrict__ resets,
    const float* __restrict__ carry,
    const float* __restrict__ lambdas,
    float*       __restrict__ out)
{
    const int b  = blockIdx.x >> 3;
    const int fl = ((blockIdx.x & 7) << 8) | threadIdx.x;
    const int f  = fl >> 3;
    const int l  = fl & 7;
    const int gid = (b << 11) | fl;

    const float lam  = lambdas[l];
    const float onem = 1.0f - lam;

    float trace = carry[gid];
    const float* fptr = features + b * FF + f;
    const int*   rptr = resets + b;
    float*       yptr = out + NCHAIN + gid;

    #pragma unroll 4
    for (int t = 0; t < TT; ++t) {
        const float x = fptr[(size_t)t * (BB * FF)];
        const int   r = rptr[(size_t)t * BB];
        const float v = fmaf(lam, trace, onem * x);
        trace = r ? x : v;
        yptr[(size_t)t * NCHAIN] = trace;
    }
    out[gid] = trace;
}

extern "C" void kernel_launch(void* const* d_in, const int* in_sizes, int n_in,
                              void* d_out, int out_size, void* d_ws, size_t ws_size,
                              hipStream_t stream) {
    const float* features = (const float*)d_in[0];
    const int*   resets   = (const int*)d_in[1];
    const float* carry    = (const float*)d_in[2];
    const float* lambdas  = (const float*)d_in[3];
    float* out = (float*)d_out;

    const size_t ws_needed = (size_t)2 * NCHUNK * NCHAIN * sizeof(float); // 4 MB
    if (ws_size < ws_needed) {
        trace_rnn_fallback<<<NCHAIN / 256, 256, 0, stream>>>(
            features, resets, carry, lambdas, out);
        return;
    }

    float* wsA = (float*)d_ws;
    float* wsE = wsA + (size_t)NCHUNK * NCHAIN;

    const int grid = NCHAIN * NCHUNK / 256;  // 2048 blocks
    phase1_kernel<<<grid, 256, 0, stream>>>(features, resets, lambdas, wsA, wsE);
    phase2_kernel<<<grid, 256, 0, stream>>>(features, resets, carry, lambdas,
                                            wsA, wsE, out);
}

// Round 3
// 37.494 us; speedup vs baseline: 2.2271x; 1.2717x over previous
//
#include <hip/hip_runtime.h>

// Problem shape (fixed by the reference setup)
#define TT 512
#define BB 32
#define FF 256
#define LL 8
#define NCHAIN (BB * FF * LL)   // 65536 chains
#define NGROUP (NCHAIN / 4)     // 16384 float4 groups (4 consecutive l's)

typedef float f32x4 __attribute__((ext_vector_type(4)));

// Decomposition: group g = (b<<9) | (f<<1) | h, h = l>>2. Chain base = 4*g.
// Per chunk: 64 blocks of 256 threads. blockLocal = blockIdx & 63;
// b = blockLocal>>1 (block-uniform -> resets is a scalar broadcast);
// idx = ((blockLocal&1)<<8)|tid; f = idx>>1; h = idx&1.
// Consecutive lanes -> consecutive 16B store slots -> 1KiB/wave stores.

template <int NCHUNK>
__global__ __launch_bounds__(256) void phase1_vec(
    const float* __restrict__ features,  // [T,B,F]
    const int*   __restrict__ resets,    // [T,B]
    const float* __restrict__ lambdas,   // [L]
    f32x4*       __restrict__ wsA,       // [NCHUNK][NGROUP]
    f32x4*       __restrict__ wsE)       // [NCHUNK][NGROUP]
{
    constexpr int TC = TT / NCHUNK;
    const int chunk      = blockIdx.x >> 6;
    const int blockLocal = blockIdx.x & 63;
    const int b   = blockLocal >> 1;
    const int idx = ((blockLocal & 1) << 8) | threadIdx.x;
    const int f   = idx >> 1;
    const int h   = idx & 1;
    const int g   = (b << 9) | idx;

    const f32x4 lam  = ((const f32x4*)lambdas)[h];
    const f32x4 onem = 1.0f - lam;
    const int   t0   = chunk * TC;

    const float* fptr = features + (size_t)t0 * (BB * FF) + b * FF + f;
    const int*   rptr = resets + (size_t)t0 * BB + b;

    f32x4 A = 1.0f;
    f32x4 E = 0.0f;
    #pragma unroll 8
    for (int t = 0; t < TC; ++t) {
        const float x = fptr[(size_t)t * (BB * FF)];
        const int   r = rptr[(size_t)t * BB];
        #pragma unroll
        for (int j = 0; j < 4; ++j) {
            const float Av = A[j] * lam[j];
            const float Ev = fmaf(lam[j], E[j], onem[j] * x);
            A[j] = r ? 0.0f : Av;
            E[j] = r ? x : Ev;
        }
    }
    wsA[(size_t)chunk * NGROUP + g] = A;
    wsE[(size_t)chunk * NGROUP + g] = E;
}

template <int NCHUNK>
__global__ __launch_bounds__(256) void phase2_vec(
    const float* __restrict__ features,
    const int*   __restrict__ resets,
    const float* __restrict__ carry,     // [B,F,L]
    const float* __restrict__ lambdas,
    const f32x4* __restrict__ wsA,
    const f32x4* __restrict__ wsE,
    f32x4*       __restrict__ out4)      // [NGROUP] final, then [T][NGROUP]
{
    constexpr int TC = TT / NCHUNK;
    const int chunk      = blockIdx.x >> 6;
    const int blockLocal = blockIdx.x & 63;
    const int b   = blockLocal >> 1;
    const int idx = ((blockLocal & 1) << 8) | threadIdx.x;
    const int f   = idx >> 1;
    const int h   = idx & 1;
    const int g   = (b << 9) | idx;

    const f32x4 lam  = ((const f32x4*)lambdas)[h];
    const f32x4 onem = 1.0f - lam;
    const int   t0   = chunk * TC;

    // Fold carry through chunks [0, chunk) -> true initial state.
    f32x4 s = ((const f32x4*)carry)[g];
    for (int cc = 0; cc < chunk; ++cc) {
        const f32x4 Ac = wsA[(size_t)cc * NGROUP + g];
        const f32x4 Ec = wsE[(size_t)cc * NGROUP + g];
        #pragma unroll
        for (int j = 0; j < 4; ++j) s[j] = fmaf(Ac[j], s[j], Ec[j]);
    }

    const float* fptr = features + (size_t)t0 * (BB * FF) + b * FF + f;
    const int*   rptr = resets + (size_t)t0 * BB + b;
    f32x4*       yptr = out4 + NGROUP + (size_t)t0 * NGROUP + g;

    #pragma unroll 4
    for (int t = 0; t < TC; ++t) {
        const float x = fptr[(size_t)t * (BB * FF)];
        const int   r = rptr[(size_t)t * BB];
        #pragma unroll
        for (int j = 0; j < 4; ++j) {
            const float v = fmaf(lam[j], s[j], onem[j] * x);
            s[j] = r ? x : v;
        }
        __builtin_nontemporal_store(s, yptr + (size_t)t * NGROUP);
    }

    if (chunk == NCHUNK - 1) out4[g] = s;  // final_trace (first in concat)
}

// Fallback (ws too small): round-1 single-pass kernel, known correct.
__global__ __launch_bounds__(256) void trace_rnn_fallback(
    const float* __restrict__ features,
    const int*   __restrict__ resets,
    const float* __restrict__ carry,
    const float* __restrict__ lambdas,
    float*       __restrict__ out)
{
    const int b  = blockIdx.x >> 3;
    const int fl = ((blockIdx.x & 7) << 8) | threadIdx.x;
    const int f  = fl >> 3;
    const int l  = fl & 7;
    const int gid = (b << 11) | fl;

    const float lam  = lambdas[l];
    const float onem = 1.0f - lam;

    float trace = carry[gid];
    const float* fptr = features + b * FF + f;
    const int*   rptr = resets + b;
    float*       yptr = out + NCHAIN + gid;

    #pragma unroll 4
    for (int t = 0; t < TT; ++t) {
        const float x = fptr[(size_t)t * (BB * FF)];
        const int   r = rptr[(size_t)t * BB];
        const float v = fmaf(lam, trace, onem * x);
        trace = r ? x : v;
        yptr[(size_t)t * NCHAIN] = trace;
    }
    out[gid] = trace;
}

extern "C" void kernel_launch(void* const* d_in, const int* in_sizes, int n_in,
                              void* d_out, int out_size, void* d_ws, size_t ws_size,
                              hipStream_t stream) {
    const float* features = (const float*)d_in[0];
    const int*   resets   = (const int*)d_in[1];
    const float* carry    = (const float*)d_in[2];
    const float* lambdas  = (const float*)d_in[3];
    float* out = (float*)d_out;

    const size_t ws16 = (size_t)2 * 16 * NGROUP * sizeof(f32x4);  // 8 MB
    const size_t ws8  = (size_t)2 * 8  * NGROUP * sizeof(f32x4);  // 4 MB

    if (ws_size >= ws16) {
        f32x4* wsA = (f32x4*)d_ws;
        f32x4* wsE = wsA + (size_t)16 * NGROUP;
        phase1_vec<16><<<16 * 64, 256, 0, stream>>>(features, resets, lambdas, wsA, wsE);
        phase2_vec<16><<<16 * 64, 256, 0, stream>>>(features, resets, carry, lambdas,
                                                    wsA, wsE, (f32x4*)out);
    } else if (ws_size >= ws8) {
        f32x4* wsA = (f32x4*)d_ws;
        f32x4* wsE = wsA + (size_t)8 * NGROUP;
        phase1_vec<8><<<8 * 64, 256, 0, stream>>>(features, resets, lambdas, wsA, wsE);
        phase2_vec<8><<<8 * 64, 256, 0, stream>>>(features, resets, carry, lambdas,
                                                  wsA, wsE, (f32x4*)out);
    } else {
        trace_rnn_fallback<<<NCHAIN / 256, 256, 0, stream>>>(
            features, resets, carry, lambdas, out);
    }
}